// Round 1
// 301.751 us; speedup vs baseline: 1.0294x; 1.0294x over previous
//
#include <hip/hip_runtime.h>
#include <stdint.h>

// Problem constants
#define SEQ   2048
#define NNODE 16384      // B*S = 8*2048

typedef short  short8  __attribute__((ext_vector_type(8)));   // 8 bf16 (4 VGPR)
typedef float  float4v __attribute__((ext_vector_type(4)));
typedef unsigned short u16;
typedef unsigned short u16x8 __attribute__((ext_vector_type(8)));
typedef short  short4v __attribute__((ext_vector_type(4)));

__device__ __forceinline__ float b2f(u16 u) {
    union { unsigned int i; float f; } x; x.i = ((unsigned int)u) << 16; return x.f;
}
__device__ __forceinline__ u16 f2b(float f) {
    union { float f; unsigned int i; } x; x.f = f;
    unsigned int u = x.i;
    unsigned int r = (u + 0x7fffu + ((u >> 16) & 1u)) >> 16;  // RNE
    return (u16)r;
}

__device__ __forceinline__ void gld16(const void* g, void* l) {
    __builtin_amdgcn_global_load_lds(
        (const __attribute__((address_space(1))) void*)g,
        (__attribute__((address_space(3))) void*)l, 16, 0, 0);
}

struct GemmP {
    const void*  A[2];
    const u16*   B[2];
    const float* bias[2];
    u16*         out[2];
};

template <int MB>
__device__ __forceinline__ void mfma4(const short8* af, const short8* bq,
                                      float4v (*acc)[4]) {
#pragma unroll
    for (int mi = 0; mi < 4; ++mi)
#pragma unroll
        for (int ni = 0; ni < 4; ++ni)
            acc[MB + mi][ni] = __builtin_amdgcn_mfma_f32_16x16x32_bf16(
                af[mi], bq[ni], acc[MB + mi][ni], 0, 0, 0);
}

// ---------------------------------------------------------------------------
// 256x256-tile bf16 GEMM, counted-vmcnt pipeline (T3+T4+T5):
//   512 thr = 8 waves (2Mx4N), per-wave 128x64 out, acc[8][4].
//   BK=32, LDS ring of 3 K-tiles (3 x (A 16K + B 16K) = 96 KB, 1 blk/CU).
//   Per K-tile: 2 phases x { ds_read frags | stage-issue tile kt+2 |
//     raw s_barrier | setprio(1) 16 MFMA setprio(0) | raw s_barrier }.
//   vmcnt never drained to 0 in the loop: bf16 path waits vmcnt(4)
//   (tile kt+1 landed, tile kt+2's 4 gld16 still in flight); AF32 path
//   reg-stages A fp32 (issue at kt, cvt+ds_write at kt+1: compiler's own
//   counted wait covers the reg dep), manual vmcnt(6) publishes B.
//   Swizzle sw(r)=(r&3)^((r>>2)&3) on 16B k-chunks: uniform 2-way banks
//   (free) on both stage writes and frag reads. Epilogue reuses LDS
//   (2 passes of 128 rows, stride 264 u16 = 33*16B) after a full
//   __syncthreads() drain (tail gld16 DMA must land before LDS reuse).
// ---------------------------------------------------------------------------
#define TILE_BODY(AC, BC, KN, AG, BG, ACV, PL, PC)                            \
    {                                                                         \
        short8 bq[4], af[4];                                                  \
        _Pragma("unroll") for (int ni = 0; ni < 4; ++ni)                      \
            bq[ni] = *(const short8*)((BC) + boff + ni * 512);                \
        _Pragma("unroll") for (int mi = 0; mi < 4; ++mi)                      \
            af[mi] = *(const short8*)((AC) + aoff + mi * 512);                \
        if constexpr (AF32) prefA32(KN, PL); else stageA16(KN, AG);           \
        __builtin_amdgcn_s_barrier();                                         \
        __builtin_amdgcn_s_setprio(1);                                        \
        mfma4<0>(af, bq, acc);                                                \
        __builtin_amdgcn_s_setprio(0);                                        \
        __builtin_amdgcn_s_barrier();                                         \
        _Pragma("unroll") for (int mi = 0; mi < 4; ++mi)                      \
            af[mi] = *(const short8*)((AC) + aoff + (4 + mi) * 512);          \
        stageB(KN, BG);                                                       \
        if constexpr (AF32) {                                                 \
            cvtWrite(PC, ACV);                                                \
            asm volatile("s_waitcnt lgkmcnt(0)" ::: "memory");                \
            asm volatile("s_waitcnt vmcnt(6)" ::: "memory");                  \
        } else {                                                              \
            asm volatile("s_waitcnt vmcnt(4)" ::: "memory");                  \
        }                                                                     \
        __builtin_amdgcn_s_barrier();                                         \
        __builtin_amdgcn_s_setprio(1);                                        \
        mfma4<4>(af, bq, acc);                                                \
        __builtin_amdgcn_s_setprio(0);                                        \
        __builtin_amdgcn_s_barrier();                                         \
    }

template <int ACT, int AF32>
__global__ __launch_bounds__(512, 2) void gemm8_k(GemmP p, int M, int N, int K) {
    __shared__ __align__(16) u16 smem[49152];   // 96 KB

    const int z = blockIdx.z;
    const u16*   __restrict__ Bg   = p.B[z];
    const float* __restrict__ bias = p.bias[z];
    const u16*   __restrict__ A16  = (const u16*)p.A[z];
    const float* __restrict__ A32  = (const float*)p.A[z];

    const int mt  = blockIdx.x * 256;
    const int nt  = blockIdx.y * 256;
    const int tid = threadIdx.x;
    const int l   = tid & 63;
    const int w   = tid >> 6;
    const int wm  = (w >> 2) * 128;
    const int wn  = (w & 3) * 64;
    const int lr  = l & 15;
    const int lk  = l >> 4;
    (void)M;

    float4v acc[8][4] = {};
    float4v paA[4], paB[4];

    // staging: thread t covers chunk-slots f = t and t+512 (rm=f>>2, cc=f&3);
    // slot cc of row rm holds global k-chunk cc^sw(rm); sw(rm+128)==sw(rm).
    const int rm0 = tid >> 2;
    const int cc0 = tid & 3;
    const int gc0 = cc0 ^ (rm0 & 3) ^ ((rm0 >> 2) & 3);
    const int rm1 = rm0 + 128;

    u16* const As0 = smem;           // A ring: 0,8192,16384 (u16)
    u16* const Bs0 = smem + 24576;   // B ring: +0,+8192,+16384

    auto stageA16 = [&](int k0, u16* dst) {
        gld16(A16 + (size_t)(mt + rm0) * K + k0 + gc0 * 8, dst + tid * 8);
        gld16(A16 + (size_t)(mt + rm1) * K + k0 + gc0 * 8, dst + (tid + 512) * 8);
    };
    auto stageB = [&](int k0, u16* dst) {
        gld16(Bg + (size_t)(nt + rm0) * K + k0 + gc0 * 8, dst + tid * 8);
        gld16(Bg + (size_t)(nt + rm1) * K + k0 + gc0 * 8, dst + (tid + 512) * 8);
    };
    auto prefA32 = [&](int k0, float4v* pa) {
        const float* s0 = A32 + (size_t)(mt + rm0) * K + k0 + gc0 * 8;
        const float* s1 = A32 + (size_t)(mt + rm1) * K + k0 + gc0 * 8;
        pa[0] = *(const float4v*)s0; pa[1] = *(const float4v*)(s0 + 4);
        pa[2] = *(const float4v*)s1; pa[3] = *(const float4v*)(s1 + 4);
    };
    auto cvtWrite = [&](const float4v* pa, u16* dst) {
        u16x8 r0, r1;
        r0[0]=f2b(pa[0][0]); r0[1]=f2b(pa[0][1]); r0[2]=f2b(pa[0][2]); r0[3]=f2b(pa[0][3]);
        r0[4]=f2b(pa[1][0]); r0[5]=f2b(pa[1][1]); r0[6]=f2b(pa[1][2]); r0[7]=f2b(pa[1][3]);
        r1[0]=f2b(pa[2][0]); r1[1]=f2b(pa[2][1]); r1[2]=f2b(pa[2][2]); r1[3]=f2b(pa[2][3]);
        r1[4]=f2b(pa[3][0]); r1[5]=f2b(pa[3][1]); r1[6]=f2b(pa[3][2]); r1[7]=f2b(pa[3][3]);
        *(u16x8*)(dst + tid * 8) = r0;
        *(u16x8*)(dst + (tid + 512) * 8) = r1;
    };

    // fragment reads: slot = lk ^ (lr&3) ^ ((lr>>2)&3), mi/ni-independent
    // (wm, wn, mi*16 contribute 0 mod 4 to both row-bit fields)
    const int fsl  = lk ^ (lr & 3) ^ ((lr >> 2) & 3);
    const int aoff = (wm + lr) * 32 + fsl * 8;
    const int boff = (wn + lr) * 32 + fsl * 8;

    const int KT = K >> 5;   // K-tiles of 32 (always even here: 32/16/8)

    // ---- prologue: stage tiles 0 and 1 ----
    if constexpr (AF32) {
        float4v p0[4];
        prefA32(0, p0);
        stageB(0, Bs0);
        prefA32(32, paB);            // A(1) -> regs, cvt at tile 0 q1
        stageB(32, Bs0 + 8192);
        cvtWrite(p0, As0);           // compiler waits vmcnt(8) for p0
        asm volatile("s_waitcnt lgkmcnt(0)" ::: "memory");
        asm volatile("s_waitcnt vmcnt(6)" ::: "memory");   // B(0) landed
    } else {
        stageA16(0, As0);          stageB(0, Bs0);
        stageA16(32, As0 + 8192);  stageB(32, Bs0 + 8192);
        asm volatile("s_waitcnt vmcnt(4)" ::: "memory");   // tile 0 landed
    }
    __builtin_amdgcn_s_barrier();

    // ---- main loop: 2 K-tiles per iter, ring slot sc = kt%3 ----
    int sc = 0;
    for (int kt = 0; kt < KT; kt += 2) {
        const int sc1 = (sc == 2) ? 0 : sc + 1;
        const int sc2 = (sc1 == 2) ? 0 : sc1 + 1;
        u16* Ae = As0 + sc  * 8192;  u16* Be = Bs0 + sc  * 8192;
        u16* Ao = As0 + sc1 * 8192;  u16* Bo = Bs0 + sc1 * 8192;
        u16* A2 = As0 + sc2 * 8192;  u16* B2 = Bs0 + sc2 * 8192;
        const int k2 = (kt + 2 < KT) ? (kt + 2) << 5 : 0;  // clamp keeps vmcnt
        const int k3 = (kt + 3 < KT) ? (kt + 3) << 5 : 0;  // counts uniform
        // even tile kt: read sc; stage(kt+2)->sc2; AF32 cvt A(kt+1)->sc1
        TILE_BODY(Ae, Be, k2, A2, B2, Ao, paA, paB)
        // odd tile kt+1: read sc1; stage(kt+3)->sc; AF32 cvt A(kt+2)->sc2
        TILE_BODY(Ao, Bo, k3, Ae, Be, A2, paB, paA)
        sc = sc2;
    }

    __syncthreads();   // full drain: tail gld16 DMA must land before LDS reuse

    // ---- epilogue: C/D layout col=lane&15, row=(lane>>4)*4+reg ----
    const int r0 = lk * 4;
    float bvv[4];
#pragma unroll
    for (int ni = 0; ni < 4; ++ni) bvv[ni] = bias[nt + wn + ni * 16 + lr];
    const int half = w >> 2;
#pragma unroll
    for (int pass = 0; pass < 2; ++pass) {
        if (half == pass) {
#pragma unroll
            for (int mi = 0; mi < 8; ++mi)
#pragma unroll
                for (int ni = 0; ni < 4; ++ni) {
                    const int lc = wn + ni * 16 + lr;
#pragma unroll
                    for (int r = 0; r < 4; ++r) {
                        float v = acc[mi][ni][r] + bvv[ni];
                        if (ACT) v = v > 0.f ? v : 0.01f * v;
                        smem[(mi * 16 + r0 + r) * 264 + lc] = f2b(v);
                    }
                }
        }
        __syncthreads();
#pragma unroll
        for (int it = 0; it < 8; ++it) {
            const int id  = it * 512 + tid;
            const int row = id >> 5, colc = id & 31;
            u16x8 vv = *(const u16x8*)(smem + (size_t)row * 264 + colc * 8);
            *(u16x8*)(p.out[z] + (size_t)(mt + pass * 128 + row) * N + nt + colc * 8) = vv;
        }
        __syncthreads();
    }
}

// ---------------------------------------------------------------------------
// LDS-tiled weight transpose+convert: fp32 [K,N] -> bf16 [N,K], 64x64 tiles
// ---------------------------------------------------------------------------
struct TP { const float* src[6]; u16* dst[6]; int K[6]; int N[6]; };

__global__ __launch_bounds__(256) void transpose_k(TP t) {
    __shared__ float tile[64][65];
    const int m = blockIdx.y;
    const int K = t.K[m], N = t.N[m];
    const int tn = N >> 6;
    const int ntiles = (K >> 6) * tn;
    const int bid = blockIdx.x;
    if (bid >= ntiles) return;
    const int k0 = (bid / tn) * 64, n0 = (bid % tn) * 64;
    const int tid = threadIdx.x;
#pragma unroll
    for (int pass = 0; pass < 4; ++pass) {
        int kk = pass * 16 + (tid >> 4);
        int nn = (tid & 15) * 4;
        float4v v = *(const float4v*)(t.src[m] + (size_t)(k0 + kk) * N + n0 + nn);
        tile[kk][nn + 0] = v[0]; tile[kk][nn + 1] = v[1];
        tile[kk][nn + 2] = v[2]; tile[kk][nn + 3] = v[3];
    }
    __syncthreads();
    const int n = tid >> 2, kc = (tid & 3) * 16;
    u16x8 a, b;
#pragma unroll
    for (int j = 0; j < 8; ++j) {
        a[j] = f2b(tile[kc + j][n]);
        b[j] = f2b(tile[kc + 8 + j][n]);
    }
    u16* d = t.dst[m] + (size_t)(n0 + n) * K + k0 + kc;
    *(u16x8*)d = a;
    *(u16x8*)(d + 8) = b;
}

// EW[t][c] = sum_e emb[t][e] * W_edge[e][c]   (64x256, fp32)
__global__ void ew_k(const float* emb, const float* W_edge, float* EW) {
    const int t = blockIdx.x, c = threadIdx.x;
    float s = 0.f;
    for (int e = 0; e < 64; ++e)
        s += emb[t * 64 + e] * W_edge[e * 256 + c];
    EW[t * 256 + c] = s;
}

// bcat = [b_msg | b_self]  (512 fp32)
__global__ void bias_cat_k(const float* bmsg, const float* bself, float* bcat) {
    const int tid = threadIdx.x;
    bcat[tid]       = bmsg[tid];
    bcat[256 + tid] = bself[tid];
}

// ---------------------------------------------------------------------------
// Epilogue: out_i = xself[i] + valid_i*(xmsg[head_i] + EW[type_i]);
//           L2-normalize; accumulate per-batch sum (later /2048).
// alpha == valid exactly (dst=arange -> singleton segments -> softmax = 1).
// xcat[i, 0:256] = xmsg_i, xcat[i, 256:512] = xself_i   (one merged GEMM)
// ---------------------------------------------------------------------------
struct EpiP {
    const u16* xcat[2];
    const int* den[2]; const int* spa[2]; const int* arc[2];
    const int* wty[2]; const int* wma[2];
    const float* EW; float* racc;
};

__global__ __launch_bounds__(256) void epi_k(EpiP p) {
    __shared__ float part[4][256];
    const int bx    = blockIdx.x;
    const int side  = bx >> 9;           // 512 blocks per side
    const int local = bx & 511;
    const int base  = local * 32;        // 32 nodes/block (same batch: 32|2048)
    const int b     = base >> 11;
    const int tid   = threadIdx.x;
    const int w = tid >> 6, l = tid & 63;

    const u16* __restrict__ xcat = p.xcat[side];

    float4v acc = {};
    for (int j = 0; j < 8; ++j) {
        const int i     = base + w * 8 + j;
        const int valid = p.den[side][i] * p.spa[side][i];
        const int srcn  = p.arc[side][i] + (i >> 11) * SEQ;
        const int t     = p.wty[side][i] * p.wma[side][i];
        short4v xs = *(const short4v*)(xcat + (size_t)i * 512 + 256 + l * 4);
        short4v xm = *(const short4v*)(xcat + (size_t)srcn * 512 + l * 4);
        float4v ew = *(const float4v*)(p.EW + (size_t)t * 256 + l * 4);
        const float vm = valid ? 1.f : 0.f;
        float4v v;
        v[0] = b2f((u16)xs[0]) + vm * (b2f((u16)xm[0]) + ew[0]);
        v[1] = b2f((u16)xs[1]) + vm * (b2f((u16)xm[1]) + ew[1]);
        v[2] = b2f((u16)xs[2]) + vm * (b2f((u16)xm[2]) + ew[2]);
        v[3] = b2f((u16)xs[3]) + vm * (b2f((u16)xm[3]) + ew[3]);
        float ss = v[0]*v[0] + v[1]*v[1] + v[2]*v[2] + v[3]*v[3];
        for (int m = 32; m >= 1; m >>= 1) ss += __shfl_xor(ss, m, 64);
        const float rn = 1.f / fmaxf(sqrtf(ss), 1e-12f);
        acc[0] += v[0] * rn; acc[1] += v[1] * rn;
        acc[2] += v[2] * rn; acc[3] += v[3] * rn;
    }
    part[w][l * 4 + 0] = acc[0];
    part[w][l * 4 + 1] = acc[1];
    part[w][l * 4 + 2] = acc[2];
    part[w][l * 4 + 3] = acc[3];
    __syncthreads();
    const float s = part[0][tid] + part[1][tid] + part[2][tid] + part[3][tid];
    atomicAdd(p.racc + ((size_t)side * 8 + b) * 256 + tid, s);
}

// out[side,b,c] = (racc[side,b,:]/2048) @ Wf[:,c] + bf[c]   (fp32 out)
__global__ void fin_k(const float* racc, const float* Wf, const float* bfv,
                      float* out) {
    __shared__ float r[256];
    const int bid = blockIdx.x;   // side*8 + b, 0..15
    const int tid = threadIdx.x;
    r[tid] = racc[bid * 256 + tid] * (1.f / 2048.f);
    __syncthreads();
    float s = bfv[tid];
    for (int k = 0; k < 256; ++k)
        s += r[k] * Wf[k * 256 + tid];
    out[bid * 256 + tid] = s;
}

// ---------------------------------------------------------------------------
extern "C" void kernel_launch(void* const* d_in, const int* in_sizes, int n_in,
                              void* d_out, int out_size, void* d_ws, size_t ws_size,
                              hipStream_t stream) {
    // setup_inputs() dict order; float tensors fp32, index tensors int32
    const float* h[2]   = {(const float*)d_in[0],  (const float*)d_in[1]};
    const int* den[2]   = {(const int*)d_in[4],  (const int*)d_in[11]};
    const int* spa[2]   = {(const int*)d_in[5],  (const int*)d_in[12]};
    const int* arc[2]   = {(const int*)d_in[7],  (const int*)d_in[14]};
    const int* wty[2]   = {(const int*)d_in[9],  (const int*)d_in[16]};
    const int* wma[2]   = {(const int*)d_in[10], (const int*)d_in[17]};
    const float* W1[2]  = {(const float*)d_in[18], (const float*)d_in[22]};
    const float* b1[2]  = {(const float*)d_in[19], (const float*)d_in[23]};
    const float* W2[2]  = {(const float*)d_in[20], (const float*)d_in[24]};
    const float* b2[2]  = {(const float*)d_in[21], (const float*)d_in[25]};
    const float* emb    = (const float*)d_in[26];
    const float* Wmsg   = (const float*)d_in[27];
    const float* bmsg   = (const float*)d_in[28];
    const float* Wedge  = (const float*)d_in[29];
    const float* Wself  = (const float*)d_in[31];
    const float* bself  = (const float*)d_in[32];
    const float* Wf     = (const float*)d_in[33];
    const float* bf_    = (const float*)d_in[34];

    char* ws = (char*)d_ws;
    size_t off = 0;
    auto alloc = [&](size_t bytes) -> void* {
        void* pp = ws + off; off += (bytes + 255) & ~(size_t)255; return pp;
    };
    u16*   x1    = (u16*)  alloc(2ull * NNODE * 512 * 2);   // 32 MB, MLP hidden
    u16*   xx    = (u16*)  alloc(2ull * NNODE * 256 * 2);   // 16 MB, x
    u16*   xcat  = (u16*)  alloc(2ull * NNODE * 512 * 2);   // 32 MB, [msg|self]
    u16*   W1T   = (u16*)  alloc(2ull * 512 * 1024 * 2);
    u16*   W2T   = (u16*)  alloc(2ull * 256 * 512 * 2);
    u16*   WcatT = (u16*)  alloc(512 * 256 * 2);            // [WmsgT ; WselfT]
    float* EW    = (float*)alloc(64 * 256 * 4);
    float* bcat  = (float*)alloc(512 * 4);
    float* racc  = (float*)alloc(2 * 8 * 256 * 4);

    // prep: weights transpose+convert to [N,K] bf16 (LDS-tiled, coalesced)
    TP tp;
    tp.src[0] = W1[0]; tp.dst[0] = W1T;              tp.K[0] = 1024; tp.N[0] = 512;
    tp.src[1] = W1[1]; tp.dst[1] = W1T + 512 * 1024; tp.K[1] = 1024; tp.N[1] = 512;
    tp.src[2] = W2[0]; tp.dst[2] = W2T;              tp.K[2] = 512;  tp.N[2] = 256;
    tp.src[3] = W2[1]; tp.dst[3] = W2T + 256 * 512;  tp.K[3] = 512;  tp.N[3] = 256;
    tp.src[4] = Wmsg;  tp.dst[4] = WcatT;            tp.K[4] = 256;  tp.N[4] = 256;
    tp.src[5] = Wself; tp.dst[5] = WcatT + 256*256;  tp.K[5] = 256;  tp.N[5] = 256;
    hipLaunchKernelGGL(transpose_k, dim3(128, 6), dim3(256), 0, stream, tp);
    hipLaunchKernelGGL(ew_k, dim3(64), dim3(256), 0, stream, emb, Wedge, EW);
    hipLaunchKernelGGL(bias_cat_k, dim3(1), dim3(256), 0, stream, bmsg, bself, bcat);
    hipMemsetAsync(racc, 0, 2 * 8 * 256 * 4, stream);

    // GEMM1 (fused fp32->bf16 A, reg-staged): [16384,1024]@[1024,512]+b1, leaky
    GemmP g1 = {};
    g1.A[0] = h[0];  g1.A[1] = h[1];
    g1.B[0] = W1T;   g1.B[1] = W1T + 512 * 1024;
    g1.bias[0] = b1[0]; g1.bias[1] = b1[1];
    g1.out[0] = x1;  g1.out[1] = x1 + (size_t)NNODE * 512;
    hipLaunchKernelGGL((gemm8_k<1, 1>), dim3(64, 2, 2), dim3(512), 0, stream,
                       g1, NNODE, 512, 1024);

    // GEMM2: [16384,512]@[512,256] + b2 -> x (bf16)
    GemmP g2 = {};
    g2.A[0] = x1;  g2.A[1] = x1 + (size_t)NNODE * 512;
    g2.B[0] = W2T; g2.B[1] = W2T + 256 * 512;
    g2.bias[0] = b2[0]; g2.bias[1] = b2[1];
    g2.out[0] = xx; g2.out[1] = xx + (size_t)NNODE * 256;
    hipLaunchKernelGGL((gemm8_k<0, 0>), dim3(64, 1, 2), dim3(512), 0, stream,
                       g2, NNODE, 256, 512);

    // GEMM3 (merged msg|self): [16384,256]@[256,512] + bcat -> xcat
    GemmP g3 = {};
    g3.A[0] = xx;    g3.A[1] = xx + (size_t)NNODE * 256;
    g3.B[0] = WcatT; g3.B[1] = WcatT;
    g3.bias[0] = bcat; g3.bias[1] = bcat;
    g3.out[0] = xcat;  g3.out[1] = xcat + (size_t)NNODE * 512;
    hipLaunchKernelGGL((gemm8_k<0, 0>), dim3(64, 2, 2), dim3(512), 0, stream,
                       g3, NNODE, 512, 256);

    // gather + mask + L2-normalize + per-batch mean accumulation
    EpiP ep;
    ep.xcat[0] = xcat; ep.xcat[1] = xcat + (size_t)NNODE * 512;
    for (int s = 0; s < 2; ++s) {
        ep.den[s] = den[s]; ep.spa[s] = spa[s]; ep.arc[s] = arc[s];
        ep.wty[s] = wty[s]; ep.wma[s] = wma[s];
    }
    ep.EW = EW; ep.racc = racc;
    hipLaunchKernelGGL(epi_k, dim3(1024), dim3(256), 0, stream, ep);

    // final projection -> d_out (fp32, src then tgt, 2*8*256)
    hipLaunchKernelGGL(fin_k, dim3(16), dim3(256), 0, stream,
                       racc, Wf, bf_, (float*)d_out);
}